// Round 3
// baseline (484.936 us; speedup 1.0000x reference)
//
#include <hip/hip_runtime.h>

// Encoder: emb-gather -> xp matmuls -> BiGRU scan -> Wt matmul ->
// dt/td tree-GRU scans (fused maxpool) -> fc1 + fc2.
// Scans: 1 block per (batch, dir/kind); recurrent weights f16 packed in
// registers as SIX ext_vector<32 x u32> SSA values (no alloca -> no scratch);
// dots via v_dot2_f32_f16; f32 carry path.

typedef _Float16 half2v __attribute__((ext_vector_type(2)));
typedef unsigned int u32x32 __attribute__((ext_vector_type(32)));

__device__ __forceinline__ float fdot2f(unsigned int a, unsigned int b, float c) {
#if __has_builtin(__builtin_amdgcn_fdot2)
  return __builtin_amdgcn_fdot2(__builtin_bit_cast(half2v, a),
                                __builtin_bit_cast(half2v, b), c, false);
#else
  half2v av = __builtin_bit_cast(half2v, a), bv = __builtin_bit_cast(half2v, b);
  return c + (float)av.x * (float)bv.x + (float)av.y * (float)bv.y;
#endif
}

__device__ __forceinline__ unsigned int packh2(float x, float y) {
  half2v p;
  p.x = (_Float16)x;
  p.y = (_Float16)y;
  return __builtin_bit_cast(unsigned int, p);
}

__device__ __forceinline__ float sigm(float x) { return 1.f / (1.f + __expf(-x)); }
__device__ __forceinline__ float tanh_fast(float x) {
  float cx = fminf(fmaxf(x, -15.f), 15.f);
  float e = __expf(2.f * cx);
  return (e - 1.f) / (e + 1.f);
}

// Load thread's weight block into 6 register-resident vectors.
// Thread owns cols {jg, jg+128} of each gate, k-rows [k0, k0+64).
#define LOAD_WVEC(Wsrc)                                                        \
  {                                                                            \
    const float* Wb = (Wsrc) + (size_t)k0 * 768 + jg;                          \
    _Pragma("unroll") for (int kk = 0; kk < 32; ++kk) {                        \
      const float* r0p = Wb + (2 * kk) * 768;                                  \
      const float* r1p = Wb + (2 * kk + 1) * 768;                              \
      w00[kk] = packh2(r0p[0], r1p[0]);                                        \
      w01[kk] = packh2(r0p[128], r1p[128]);                                    \
      w10[kk] = packh2(r0p[256], r1p[256]);                                    \
      w11[kk] = packh2(r0p[384], r1p[384]);                                    \
      w20[kk] = packh2(r0p[512], r1p[512]);                                    \
      w21[kk] = packh2(r0p[640], r1p[640]);                                    \
    }                                                                          \
  }

// Dot phase: read 32 packed h pairs from LDS (8 x b128), 192 dot2, write parts.
#define DOT_PHASE(HSRC)                                                        \
  {                                                                            \
    float acc00 = 0, acc01 = 0, acc10 = 0, acc11 = 0, acc20 = 0, acc21 = 0;    \
    const uint4* hv = (const uint4*)(HSRC);                                    \
    _Pragma("unroll") for (int blkk = 0; blkk < 8; ++blkk) {                   \
      uint4 u = hv[blkk];                                                      \
      acc00 = fdot2f(w00[4 * blkk + 0], u.x, acc00);                           \
      acc01 = fdot2f(w01[4 * blkk + 0], u.x, acc01);                           \
      acc10 = fdot2f(w10[4 * blkk + 0], u.x, acc10);                           \
      acc11 = fdot2f(w11[4 * blkk + 0], u.x, acc11);                           \
      acc20 = fdot2f(w20[4 * blkk + 0], u.x, acc20);                           \
      acc21 = fdot2f(w21[4 * blkk + 0], u.x, acc21);                           \
      acc00 = fdot2f(w00[4 * blkk + 1], u.y, acc00);                           \
      acc01 = fdot2f(w01[4 * blkk + 1], u.y, acc01);                           \
      acc10 = fdot2f(w10[4 * blkk + 1], u.y, acc10);                           \
      acc11 = fdot2f(w11[4 * blkk + 1], u.y, acc11);                           \
      acc20 = fdot2f(w20[4 * blkk + 1], u.y, acc20);                           \
      acc21 = fdot2f(w21[4 * blkk + 1], u.y, acc21);                           \
      acc00 = fdot2f(w00[4 * blkk + 2], u.z, acc00);                           \
      acc01 = fdot2f(w01[4 * blkk + 2], u.z, acc01);                           \
      acc10 = fdot2f(w10[4 * blkk + 2], u.z, acc10);                           \
      acc11 = fdot2f(w11[4 * blkk + 2], u.z, acc11);                           \
      acc20 = fdot2f(w20[4 * blkk + 2], u.z, acc20);                           \
      acc21 = fdot2f(w21[4 * blkk + 2], u.z, acc21);                           \
      acc00 = fdot2f(w00[4 * blkk + 3], u.w, acc00);                           \
      acc01 = fdot2f(w01[4 * blkk + 3], u.w, acc01);                           \
      acc10 = fdot2f(w10[4 * blkk + 3], u.w, acc10);                           \
      acc11 = fdot2f(w11[4 * blkk + 3], u.w, acc11);                           \
      acc20 = fdot2f(w20[4 * blkk + 3], u.w, acc20);                           \
      acc21 = fdot2f(w21[4 * blkk + 3], u.w, acc21);                           \
    }                                                                          \
    part[q2][0][jg] = acc00;                                                   \
    part[q2][0][128 + jg] = acc01;                                             \
    part[q2][1][jg] = acc10;                                                   \
    part[q2][1][128 + jg] = acc11;                                             \
    part[q2][2][jg] = acc20;                                                   \
    part[q2][2][128 + jg] = acc21;                                             \
  }

// ---------------- embedding gathers ----------------
__global__ void gather_emb(const int* __restrict__ xs, const int* __restrict__ labels,
                           const float* __restrict__ embW, float* __restrict__ emb) {
  const int row = blockIdx.x;
  const int t = threadIdx.x;
  const float4* W4 = (const float4*)embW;
  float4* dst = (float4*)(emb + (size_t)row * 512);
  if (t < 64)
    dst[t] = W4[(size_t)xs[row] * 64 + t];
  else
    dst[t] = W4[(size_t)labels[row] * 64 + (t - 64)];
}

__global__ void gather_rel(const int* __restrict__ rels, const float* __restrict__ relW,
                           float* __restrict__ outputs) {
  const int row = blockIdx.x;
  const int t = threadIdx.x;  // 64
  const float4* W4 = (const float4*)relW;
  float4* dst = (float4*)(outputs + (size_t)row * 512 + 256);
  dst[t] = W4[(size_t)rels[row] * 64 + t];
}

// ---------------- generic f32 tiled matmul: C[M,N] = A[M,K]@W[K,N] + bias ----------------
__global__ __launch_bounds__(256, 2) void matmul_f32(const float* __restrict__ A,
                                                     const float* __restrict__ W,
                                                     const float* __restrict__ bias,
                                                     float* __restrict__ C, int K, int N,
                                                     int lda, int ldc) {
  __shared__ float As[16][68];
  __shared__ float Bs[16][64];
  const int t = threadIdx.x;
  const int bm = blockIdx.y * 64, bn = blockIdx.x * 64;
  const int tn4 = (t & 15) * 4, tm4 = (t >> 4) * 4;
  const int lm = t >> 2, lk4 = (t & 3) * 4;
  const int wk = t >> 4, wn4 = (t & 15) * 4;
  float acc[4][4] = {};
  for (int kt = 0; kt < K; kt += 16) {
    float4 a4 = *(const float4*)(A + (size_t)(bm + lm) * lda + kt + lk4);
    As[lk4 + 0][lm] = a4.x;
    As[lk4 + 1][lm] = a4.y;
    As[lk4 + 2][lm] = a4.z;
    As[lk4 + 3][lm] = a4.w;
    *(float4*)(&Bs[wk][wn4]) = *(const float4*)(W + (size_t)(kt + wk) * N + bn + wn4);
    __syncthreads();
#pragma unroll
    for (int k = 0; k < 16; ++k) {
      float4 av = *(const float4*)(&As[k][tm4]);
      float4 bv = *(const float4*)(&Bs[k][tn4]);
      float aa[4] = {av.x, av.y, av.z, av.w};
      float bb[4] = {bv.x, bv.y, bv.z, bv.w};
#pragma unroll
      for (int i = 0; i < 4; ++i)
#pragma unroll
        for (int j = 0; j < 4; ++j) acc[i][j] = fmaf(aa[i], bb[j], acc[i][j]);
    }
    __syncthreads();
  }
#pragma unroll
  for (int i = 0; i < 4; ++i) {
    float4 o;
    o.x = acc[i][0] + bias[bn + tn4 + 0];
    o.y = acc[i][1] + bias[bn + tn4 + 1];
    o.z = acc[i][2] + bias[bn + tn4 + 2];
    o.w = acc[i][3] + bias[bn + tn4 + 3];
    *(float4*)(C + (size_t)(bm + tm4 + i) * ldc + bn + tn4) = o;
  }
}

// ---------------- BiGRU scan: 1 block per (batch, dir) ----------------
__global__ __launch_bounds__(512, 1) void gru_scan(
    const float* __restrict__ Wh_f, const float* __restrict__ Wh_b,
    const float* __restrict__ bh_f, const float* __restrict__ bh_b,
    const float* __restrict__ xp_f, const float* __restrict__ xp_b,
    float* __restrict__ grus_cat) {
  const int b = blockIdx.x & 31;
  const int dir = blockIdx.x >> 5;
  const float* __restrict__ Wh = dir ? Wh_b : Wh_f;
  const float* __restrict__ bh = dir ? bh_b : bh_f;
  const float* __restrict__ xp = dir ? xp_b : xp_f;

  __shared__ __align__(16) unsigned int h2[128];  // packed half2 of h
  __shared__ float hf[256];                       // f32 h carry
  __shared__ float part[4][3][256];               // [kgroup][gate][j]

  const int t = threadIdx.x;
  const int jg = t & 127;
  const int q2 = t >> 7;
  const int k0 = q2 * 64;

  u32x32 w00, w01, w10, w11, w20, w21;
  LOAD_WVEC(Wh);

  // per-thread biases (t < 128 lanes own j-pair 2t, 2t+1)
  float br0 = 0, br1 = 0, bz0 = 0, bz1 = 0, bn0 = 0, bn1 = 0;
  if (t < 128) {
    br0 = bh[2 * t];       br1 = bh[2 * t + 1];
    bz0 = bh[256 + 2 * t]; bz1 = bh[256 + 2 * t + 1];
    bn0 = bh[512 + 2 * t]; bn1 = bh[512 + 2 * t + 1];
  }

  if (t < 128) h2[t] = 0u;
  if (t < 256) hf[t] = 0.f;
  __syncthreads();

  for (int s = 0; s < 64; ++s) {
    const int nn = dir ? (63 - s) : s;
    float2 pxr, pxz, pxn;
    if (t < 128) {
      const float* xrow = xp + (size_t)(b * 64 + nn) * 768;
      pxr = *(const float2*)(xrow + 2 * t);
      pxz = *(const float2*)(xrow + 256 + 2 * t);
      pxn = *(const float2*)(xrow + 512 + 2 * t);
    }

    DOT_PHASE(h2 + q2 * 32);
    __syncthreads();

    if (t < 128) {
      float s0r = 0, s1r = 0, s0z = 0, s1z = 0, s0n = 0, s1n = 0;
#pragma unroll
      for (int q = 0; q < 4; ++q) {
        float2 pr = *(const float2*)(&part[q][0][2 * t]); s0r += pr.x; s1r += pr.y;
        float2 pz = *(const float2*)(&part[q][1][2 * t]); s0z += pz.x; s1z += pz.y;
        float2 pn = *(const float2*)(&part[q][2][2 * t]); s0n += pn.x; s1n += pn.y;
      }
      float r0 = sigm(pxr.x + s0r + br0), r1 = sigm(pxr.y + s1r + br1);
      float z0 = sigm(pxz.x + s0z + bz0), z1 = sigm(pxz.y + s1z + bz1);
      float n0 = tanh_fast(pxn.x + r0 * (s0n + bn0));
      float n1 = tanh_fast(pxn.y + r1 * (s1n + bn1));
      float hp0 = hf[2 * t], hp1 = hf[2 * t + 1];
      float h0 = (1.f - z0) * n0 + z0 * hp0;
      float h1 = (1.f - z1) * n1 + z1 * hp1;
      hf[2 * t] = h0;
      hf[2 * t + 1] = h1;
      h2[t] = packh2(h0, h1);
      float2 o;
      o.x = h0;
      o.y = h1;
      *(float2*)(grus_cat + (size_t)(b * 64 + nn) * 512 + dir * 256 + 2 * t) = o;
    }
    __syncthreads();
  }
}

// ---------------- tree scans with fused maxpool: 1 block per (batch, kind) ----------------
__global__ __launch_bounds__(512, 1) void tree_scan(
    const float* __restrict__ Uh_dt, const float* __restrict__ Uh_td,
    const float* __restrict__ xp_dt, const float* __restrict__ xp_td,
    const int* __restrict__ heads, float* __restrict__ ctx) {
  const int b = blockIdx.x & 31;
  const int istd = blockIdx.x >> 5;  // 0 = dt (bottom-up), 1 = td (top-down)
  const float* __restrict__ Uh = istd ? Uh_td : Uh_dt;
  const float* __restrict__ xp = istd ? xp_td : xp_dt;

  __shared__ float S[65][256];                        // f32 state (C or Hout); row 64 = zeros
  __shared__ __align__(16) unsigned int S2[65][128];  // packed f16 mirror
  __shared__ float part[4][3][256];
  __shared__ int hd[64];

  const int t = threadIdx.x;
  const int jg = t & 127;
  const int q2 = t >> 7;
  const int k0 = q2 * 64;

  u32x32 w00, w01, w10, w11, w20, w21;
  LOAD_WVEC(Uh);

  for (int i = t; i < 65 * 256; i += 512) ((float*)S)[i] = 0.f;
  for (int i = t; i < 65 * 128; i += 512) ((unsigned int*)S2)[i] = 0u;
  if (t < 64) hd[t] = heads[b * 64 + t];
  __syncthreads();

  float mx0 = -1e30f, mx1 = -1e30f;  // running maxpool (t < 128)

  for (int s = 0; s < 64; ++s) {
    const int idx = istd ? s : (63 - s);
    const int par = hd[idx];
    const int srow = istd ? (par >= 0 ? par : 64) : idx;

    float2 pxr, pxz, pxn;
    if (t < 128) {
      const float* xrow = xp + (size_t)(b * 64 + idx) * 768;
      pxr = *(const float2*)(xrow + 2 * t);
      pxz = *(const float2*)(xrow + 256 + 2 * t);
      pxn = *(const float2*)(xrow + 512 + 2 * t);
    }

    DOT_PHASE(&S2[srow][q2 * 32]);
    __syncthreads();

    if (t < 128) {
      float s0r = 0, s1r = 0, s0z = 0, s1z = 0, s0n = 0, s1n = 0;
#pragma unroll
      for (int q = 0; q < 4; ++q) {
        float2 pr = *(const float2*)(&part[q][0][2 * t]); s0r += pr.x; s1r += pr.y;
        float2 pz = *(const float2*)(&part[q][1][2 * t]); s0z += pz.x; s1z += pz.y;
        float2 pn = *(const float2*)(&part[q][2][2 * t]); s0n += pn.x; s1n += pn.y;
      }
      float r0 = sigm(pxr.x + s0r), r1 = sigm(pxr.y + s1r);
      float z0 = sigm(pxz.x + s0z), z1 = sigm(pxz.y + s1z);
      float n0 = tanh_fast(pxn.x + r0 * s0n), n1 = tanh_fast(pxn.y + r1 * s1n);
      float hp0 = S[srow][2 * t], hp1 = S[srow][2 * t + 1];
      float h0 = (1.f - z0) * n0 + z0 * hp0;
      float h1 = (1.f - z1) * n1 + z1 * hp1;
      mx0 = fmaxf(mx0, h0);
      mx1 = fmaxf(mx1, h1);
      if (istd) {
        S[idx][2 * t] = h0;
        S[idx][2 * t + 1] = h1;
        S2[idx][t] = packh2(h0, h1);
      } else if (par >= 0) {
        float c0 = S[par][2 * t] + h0;
        float c1 = S[par][2 * t + 1] + h1;
        S[par][2 * t] = c0;
        S[par][2 * t + 1] = c1;
        S2[par][t] = packh2(c0, c1);
      }
    }
    __syncthreads();
  }

  if (t < 128) {
    float2 o;
    o.x = mx0;
    o.y = mx1;
    *(float2*)(ctx + (size_t)b * 512 + istd * 256 + 2 * t) = o;
  }
}

// ---------------- fc1 + fc2 ----------------
__global__ __launch_bounds__(128) void final_k(const float* __restrict__ ctx_g,
                                               const float* __restrict__ fcW,
                                               const float* __restrict__ fcb,
                                               const float* __restrict__ fc2W,
                                               const float* __restrict__ fc2b,
                                               float* __restrict__ out) {
  const int b = blockIdx.x;
  const int t = threadIdx.x;
  __shared__ float ctx[512];
  __shared__ float f1[100];
  for (int i = t; i < 512; i += 128) ctx[i] = ctx_g[(size_t)b * 512 + i];
  __syncthreads();
  if (t < 100) {
    float a = fcb[t];
    for (int k = 0; k < 512; ++k) a = fmaf(ctx[k], fcW[k * 100 + t], a);
    f1[t] = a;
  }
  __syncthreads();
  if (t < 5) {
    float a = fc2b[t];
    for (int k = 0; k < 100; ++k) a = fmaf(f1[k], fc2W[k * 5 + t], a);
    out[b * 5 + t] = a;
  }
}

extern "C" void kernel_launch(void* const* d_in, const int* in_sizes, int n_in, void* d_out,
                              int out_size, void* d_ws, size_t ws_size, hipStream_t stream) {
  const int* xs = (const int*)d_in[0];
  const int* heads = (const int*)d_in[1];
  const int* rels = (const int*)d_in[2];
  const int* labels = (const int*)d_in[3];
  const float* emb_W = (const float*)d_in[9];
  const float* rel_W = (const float*)d_in[10];
  const float* Wi_f = (const float*)d_in[11];
  const float* Wh_f = (const float*)d_in[12];
  const float* bi_f = (const float*)d_in[13];
  const float* bh_f = (const float*)d_in[14];
  const float* Wi_b = (const float*)d_in[15];
  const float* Wh_b = (const float*)d_in[16];
  const float* bi_b = (const float*)d_in[17];
  const float* bh_b = (const float*)d_in[18];
  const float* Wt = (const float*)d_in[19];
  const float* bt = (const float*)d_in[20];
  const float* dt_Wx = (const float*)d_in[21];
  const float* dt_Uh = (const float*)d_in[22];
  const float* dt_b = (const float*)d_in[23];
  const float* td_Wx = (const float*)d_in[24];
  const float* td_Uh = (const float*)d_in[25];
  const float* td_b = (const float*)d_in[26];
  const float* fc_W = (const float*)d_in[27];
  const float* fc_b = (const float*)d_in[28];
  const float* fc2_W = (const float*)d_in[29];
  const float* fc2_b = (const float*)d_in[30];

  float* ws = (float*)d_ws;
  float* emb = ws;                  // 2048*512
  float* xp_f = ws + 1048576;       // 2048*768
  float* xp_b = xp_f + 1572864;     // 2048*768
  float* grus = xp_b + 1572864;     // 2048*512
  float* outputs = grus + 1048576;  // 2048*512
  float* ctx = outputs + 1048576;   // 32*512
  float* xp_dt = xp_f;              // alias (xp_f dead after gru_scan)
  float* xp_td = xp_b;              // alias

  gather_emb<<<2048, 128, 0, stream>>>(xs, labels, emb_W, emb);
  matmul_f32<<<dim3(12, 32), 256, 0, stream>>>(emb, Wi_f, bi_f, xp_f, 512, 768, 512, 768);
  matmul_f32<<<dim3(12, 32), 256, 0, stream>>>(emb, Wi_b, bi_b, xp_b, 512, 768, 512, 768);
  gru_scan<<<64, 512, 0, stream>>>(Wh_f, Wh_b, bh_f, bh_b, xp_f, xp_b, grus);
  gather_rel<<<2048, 64, 0, stream>>>(rels, rel_W, outputs);
  matmul_f32<<<dim3(4, 32), 256, 0, stream>>>(grus, Wt, bt, outputs, 512, 256, 512, 512);
  matmul_f32<<<dim3(12, 32), 256, 0, stream>>>(outputs, dt_Wx, dt_b, xp_dt, 512, 768, 512, 768);
  matmul_f32<<<dim3(12, 32), 256, 0, stream>>>(outputs, td_Wx, td_b, xp_td, 512, 768, 512, 768);
  tree_scan<<<64, 512, 0, stream>>>(dt_Uh, td_Uh, xp_dt, xp_td, heads, ctx);
  final_k<<<32, 128, 0, stream>>>(ctx, fc_W, fc_b, fc2_W, fc2_b, (float*)d_out);
}

// Round 4
// 484.451 us; speedup vs baseline: 1.0010x; 1.0010x over previous
//
#include <hip/hip_runtime.h>

// Encoder: emb-gather -> xp matmuls -> BiGRU scan -> Wt matmul ->
// dt/td tree-GRU scans (fused maxpool) -> fc1 + fc2.
// Scans: 1 block per (batch, dir/kind); recurrent weights f16 packed in
// registers as SIX ext_vector<32 x u32> SSA values; dots via v_dot2_f32_f16;
// f32 carry path. amdgpu_waves_per_eu(2,2) raises the VGPR cap to 256 so the
// 192 weight regs stay resident (round-3 failure: allocator capped at 128 ->
// forced spill -> L2-scratch-read-bound scans).

typedef _Float16 half2v __attribute__((ext_vector_type(2)));
typedef unsigned int u32x32 __attribute__((ext_vector_type(32)));

__device__ __forceinline__ float fdot2f(unsigned int a, unsigned int b, float c) {
#if __has_builtin(__builtin_amdgcn_fdot2)
  return __builtin_amdgcn_fdot2(__builtin_bit_cast(half2v, a),
                                __builtin_bit_cast(half2v, b), c, false);
#else
  half2v av = __builtin_bit_cast(half2v, a), bv = __builtin_bit_cast(half2v, b);
  return c + (float)av.x * (float)bv.x + (float)av.y * (float)bv.y;
#endif
}

__device__ __forceinline__ unsigned int packh2(float x, float y) {
  half2v p;
  p.x = (_Float16)x;
  p.y = (_Float16)y;
  return __builtin_bit_cast(unsigned int, p);
}

__device__ __forceinline__ float sigm(float x) { return 1.f / (1.f + __expf(-x)); }
__device__ __forceinline__ float tanh_fast(float x) {
  float cx = fminf(fmaxf(x, -15.f), 15.f);
  float e = __expf(2.f * cx);
  return (e - 1.f) / (e + 1.f);
}

// Load thread's weight block into 6 register-resident vectors.
// Thread owns cols {jg, jg+128} of each gate, k-rows [k0, k0+64).
#define LOAD_WVEC(Wsrc)                                                        \
  {                                                                            \
    const float* Wb = (Wsrc) + (size_t)k0 * 768 + jg;                          \
    _Pragma("unroll") for (int kk = 0; kk < 32; ++kk) {                        \
      const float* r0p = Wb + (2 * kk) * 768;                                  \
      const float* r1p = Wb + (2 * kk + 1) * 768;                              \
      w00[kk] = packh2(r0p[0], r1p[0]);                                        \
      w01[kk] = packh2(r0p[128], r1p[128]);                                    \
      w10[kk] = packh2(r0p[256], r1p[256]);                                    \
      w11[kk] = packh2(r0p[384], r1p[384]);                                    \
      w20[kk] = packh2(r0p[512], r1p[512]);                                    \
      w21[kk] = packh2(r0p[640], r1p[640]);                                    \
    }                                                                          \
  }

// Dot phase: read 32 packed h pairs from LDS (8 x b128), 192 dot2, write parts.
#define DOT_PHASE(HSRC)                                                        \
  {                                                                            \
    float acc00 = 0, acc01 = 0, acc10 = 0, acc11 = 0, acc20 = 0, acc21 = 0;    \
    const uint4* hv = (const uint4*)(HSRC);                                    \
    _Pragma("unroll") for (int blkk = 0; blkk < 8; ++blkk) {                   \
      uint4 u = hv[blkk];                                                      \
      acc00 = fdot2f(w00[4 * blkk + 0], u.x, acc00);                           \
      acc01 = fdot2f(w01[4 * blkk + 0], u.x, acc01);                           \
      acc10 = fdot2f(w10[4 * blkk + 0], u.x, acc10);                           \
      acc11 = fdot2f(w11[4 * blkk + 0], u.x, acc11);                           \
      acc20 = fdot2f(w20[4 * blkk + 0], u.x, acc20);                           \
      acc21 = fdot2f(w21[4 * blkk + 0], u.x, acc21);                           \
      acc00 = fdot2f(w00[4 * blkk + 1], u.y, acc00);                           \
      acc01 = fdot2f(w01[4 * blkk + 1], u.y, acc01);                           \
      acc10 = fdot2f(w10[4 * blkk + 1], u.y, acc10);                           \
      acc11 = fdot2f(w11[4 * blkk + 1], u.y, acc11);                           \
      acc20 = fdot2f(w20[4 * blkk + 1], u.y, acc20);                           \
      acc21 = fdot2f(w21[4 * blkk + 1], u.y, acc21);                           \
      acc00 = fdot2f(w00[4 * blkk + 2], u.z, acc00);                           \
      acc01 = fdot2f(w01[4 * blkk + 2], u.z, acc01);                           \
      acc10 = fdot2f(w10[4 * blkk + 2], u.z, acc10);                           \
      acc11 = fdot2f(w11[4 * blkk + 2], u.z, acc11);                           \
      acc20 = fdot2f(w20[4 * blkk + 2], u.z, acc20);                           \
      acc21 = fdot2f(w21[4 * blkk + 2], u.z, acc21);                           \
      acc00 = fdot2f(w00[4 * blkk + 3], u.w, acc00);                           \
      acc01 = fdot2f(w01[4 * blkk + 3], u.w, acc01);                           \
      acc10 = fdot2f(w10[4 * blkk + 3], u.w, acc10);                           \
      acc11 = fdot2f(w11[4 * blkk + 3], u.w, acc11);                           \
      acc20 = fdot2f(w20[4 * blkk + 3], u.w, acc20);                           \
      acc21 = fdot2f(w21[4 * blkk + 3], u.w, acc21);                           \
    }                                                                          \
    part[q2][0][jg] = acc00;                                                   \
    part[q2][0][128 + jg] = acc01;                                             \
    part[q2][1][jg] = acc10;                                                   \
    part[q2][1][128 + jg] = acc11;                                             \
    part[q2][2][jg] = acc20;                                                   \
    part[q2][2][128 + jg] = acc21;                                             \
  }

// ---------------- embedding gathers ----------------
__global__ void gather_emb(const int* __restrict__ xs, const int* __restrict__ labels,
                           const float* __restrict__ embW, float* __restrict__ emb) {
  const int row = blockIdx.x;
  const int t = threadIdx.x;
  const float4* W4 = (const float4*)embW;
  float4* dst = (float4*)(emb + (size_t)row * 512);
  if (t < 64)
    dst[t] = W4[(size_t)xs[row] * 64 + t];
  else
    dst[t] = W4[(size_t)labels[row] * 64 + (t - 64)];
}

__global__ void gather_rel(const int* __restrict__ rels, const float* __restrict__ relW,
                           float* __restrict__ outputs) {
  const int row = blockIdx.x;
  const int t = threadIdx.x;  // 64
  const float4* W4 = (const float4*)relW;
  float4* dst = (float4*)(outputs + (size_t)row * 512 + 256);
  dst[t] = W4[(size_t)rels[row] * 64 + t];
}

// ---------------- generic f32 tiled matmul: C[M,N] = A[M,K]@W[K,N] + bias ----------------
__global__ __launch_bounds__(256, 2) void matmul_f32(const float* __restrict__ A,
                                                     const float* __restrict__ W,
                                                     const float* __restrict__ bias,
                                                     float* __restrict__ C, int K, int N,
                                                     int lda, int ldc) {
  __shared__ float As[16][68];
  __shared__ float Bs[16][64];
  const int t = threadIdx.x;
  const int bm = blockIdx.y * 64, bn = blockIdx.x * 64;
  const int tn4 = (t & 15) * 4, tm4 = (t >> 4) * 4;
  const int lm = t >> 2, lk4 = (t & 3) * 4;
  const int wk = t >> 4, wn4 = (t & 15) * 4;
  float acc[4][4] = {};
  for (int kt = 0; kt < K; kt += 16) {
    float4 a4 = *(const float4*)(A + (size_t)(bm + lm) * lda + kt + lk4);
    As[lk4 + 0][lm] = a4.x;
    As[lk4 + 1][lm] = a4.y;
    As[lk4 + 2][lm] = a4.z;
    As[lk4 + 3][lm] = a4.w;
    *(float4*)(&Bs[wk][wn4]) = *(const float4*)(W + (size_t)(kt + wk) * N + bn + wn4);
    __syncthreads();
#pragma unroll
    for (int k = 0; k < 16; ++k) {
      float4 av = *(const float4*)(&As[k][tm4]);
      float4 bv = *(const float4*)(&Bs[k][tn4]);
      float aa[4] = {av.x, av.y, av.z, av.w};
      float bb[4] = {bv.x, bv.y, bv.z, bv.w};
#pragma unroll
      for (int i = 0; i < 4; ++i)
#pragma unroll
        for (int j = 0; j < 4; ++j) acc[i][j] = fmaf(aa[i], bb[j], acc[i][j]);
    }
    __syncthreads();
  }
#pragma unroll
  for (int i = 0; i < 4; ++i) {
    float4 o;
    o.x = acc[i][0] + bias[bn + tn4 + 0];
    o.y = acc[i][1] + bias[bn + tn4 + 1];
    o.z = acc[i][2] + bias[bn + tn4 + 2];
    o.w = acc[i][3] + bias[bn + tn4 + 3];
    *(float4*)(C + (size_t)(bm + tm4 + i) * ldc + bn + tn4) = o;
  }
}

// ---------------- BiGRU scan: 1 block per (batch, dir) ----------------
__global__ __attribute__((amdgpu_flat_work_group_size(512, 512),
                          amdgpu_waves_per_eu(2, 2))) void gru_scan(
    const float* __restrict__ Wh_f, const float* __restrict__ Wh_b,
    const float* __restrict__ bh_f, const float* __restrict__ bh_b,
    const float* __restrict__ xp_f, const float* __restrict__ xp_b,
    float* __restrict__ grus_cat) {
  const int b = blockIdx.x & 31;
  const int dir = blockIdx.x >> 5;
  const float* __restrict__ Wh = dir ? Wh_b : Wh_f;
  const float* __restrict__ bh = dir ? bh_b : bh_f;
  const float* __restrict__ xp = dir ? xp_b : xp_f;

  __shared__ __align__(16) unsigned int h2[128];  // packed half2 of h
  __shared__ float hf[256];                       // f32 h carry
  __shared__ float part[4][3][256];               // [kgroup][gate][j]

  const int t = threadIdx.x;
  const int jg = t & 127;
  const int q2 = t >> 7;
  const int k0 = q2 * 64;

  u32x32 w00, w01, w10, w11, w20, w21;
  LOAD_WVEC(Wh);

  // per-thread biases (t < 128 lanes own j-pair 2t, 2t+1)
  float br0 = 0, br1 = 0, bz0 = 0, bz1 = 0, bn0 = 0, bn1 = 0;
  if (t < 128) {
    br0 = bh[2 * t];       br1 = bh[2 * t + 1];
    bz0 = bh[256 + 2 * t]; bz1 = bh[256 + 2 * t + 1];
    bn0 = bh[512 + 2 * t]; bn1 = bh[512 + 2 * t + 1];
  }

  if (t < 128) h2[t] = 0u;
  if (t < 256) hf[t] = 0.f;
  __syncthreads();

  for (int s = 0; s < 64; ++s) {
    const int nn = dir ? (63 - s) : s;
    float2 pxr, pxz, pxn;
    if (t < 128) {
      const float* xrow = xp + (size_t)(b * 64 + nn) * 768;
      pxr = *(const float2*)(xrow + 2 * t);
      pxz = *(const float2*)(xrow + 256 + 2 * t);
      pxn = *(const float2*)(xrow + 512 + 2 * t);
    }

    DOT_PHASE(h2 + q2 * 32);
    __syncthreads();

    if (t < 128) {
      float s0r = 0, s1r = 0, s0z = 0, s1z = 0, s0n = 0, s1n = 0;
#pragma unroll
      for (int q = 0; q < 4; ++q) {
        float2 pr = *(const float2*)(&part[q][0][2 * t]); s0r += pr.x; s1r += pr.y;
        float2 pz = *(const float2*)(&part[q][1][2 * t]); s0z += pz.x; s1z += pz.y;
        float2 pn = *(const float2*)(&part[q][2][2 * t]); s0n += pn.x; s1n += pn.y;
      }
      float r0 = sigm(pxr.x + s0r + br0), r1 = sigm(pxr.y + s1r + br1);
      float z0 = sigm(pxz.x + s0z + bz0), z1 = sigm(pxz.y + s1z + bz1);
      float n0 = tanh_fast(pxn.x + r0 * (s0n + bn0));
      float n1 = tanh_fast(pxn.y + r1 * (s1n + bn1));
      float hp0 = hf[2 * t], hp1 = hf[2 * t + 1];
      float h0 = (1.f - z0) * n0 + z0 * hp0;
      float h1 = (1.f - z1) * n1 + z1 * hp1;
      hf[2 * t] = h0;
      hf[2 * t + 1] = h1;
      h2[t] = packh2(h0, h1);
      float2 o;
      o.x = h0;
      o.y = h1;
      *(float2*)(grus_cat + (size_t)(b * 64 + nn) * 512 + dir * 256 + 2 * t) = o;
    }
    __syncthreads();
  }
}

// ---------------- tree scans with fused maxpool: 1 block per (batch, kind) ----------------
__global__ __attribute__((amdgpu_flat_work_group_size(512, 512),
                          amdgpu_waves_per_eu(2, 2))) void tree_scan(
    const float* __restrict__ Uh_dt, const float* __restrict__ Uh_td,
    const float* __restrict__ xp_dt, const float* __restrict__ xp_td,
    const int* __restrict__ heads, float* __restrict__ ctx) {
  const int b = blockIdx.x & 31;
  const int istd = blockIdx.x >> 5;  // 0 = dt (bottom-up), 1 = td (top-down)
  const float* __restrict__ Uh = istd ? Uh_td : Uh_dt;
  const float* __restrict__ xp = istd ? xp_td : xp_dt;

  __shared__ float S[65][256];                        // f32 state (C or Hout); row 64 = zeros
  __shared__ __align__(16) unsigned int S2[65][128];  // packed f16 mirror
  __shared__ float part[4][3][256];
  __shared__ int hd[64];

  const int t = threadIdx.x;
  const int jg = t & 127;
  const int q2 = t >> 7;
  const int k0 = q2 * 64;

  u32x32 w00, w01, w10, w11, w20, w21;
  LOAD_WVEC(Uh);

  for (int i = t; i < 65 * 256; i += 512) ((float*)S)[i] = 0.f;
  for (int i = t; i < 65 * 128; i += 512) ((unsigned int*)S2)[i] = 0u;
  if (t < 64) hd[t] = heads[b * 64 + t];
  __syncthreads();

  float mx0 = -1e30f, mx1 = -1e30f;  // running maxpool (t < 128)

  for (int s = 0; s < 64; ++s) {
    const int idx = istd ? s : (63 - s);
    const int par = hd[idx];
    const int srow = istd ? (par >= 0 ? par : 64) : idx;

    float2 pxr, pxz, pxn;
    if (t < 128) {
      const float* xrow = xp + (size_t)(b * 64 + idx) * 768;
      pxr = *(const float2*)(xrow + 2 * t);
      pxz = *(const float2*)(xrow + 256 + 2 * t);
      pxn = *(const float2*)(xrow + 512 + 2 * t);
    }

    DOT_PHASE(&S2[srow][q2 * 32]);
    __syncthreads();

    if (t < 128) {
      float s0r = 0, s1r = 0, s0z = 0, s1z = 0, s0n = 0, s1n = 0;
#pragma unroll
      for (int q = 0; q < 4; ++q) {
        float2 pr = *(const float2*)(&part[q][0][2 * t]); s0r += pr.x; s1r += pr.y;
        float2 pz = *(const float2*)(&part[q][1][2 * t]); s0z += pz.x; s1z += pz.y;
        float2 pn = *(const float2*)(&part[q][2][2 * t]); s0n += pn.x; s1n += pn.y;
      }
      float r0 = sigm(pxr.x + s0r), r1 = sigm(pxr.y + s1r);
      float z0 = sigm(pxz.x + s0z), z1 = sigm(pxz.y + s1z);
      float n0 = tanh_fast(pxn.x + r0 * s0n), n1 = tanh_fast(pxn.y + r1 * s1n);
      float hp0 = S[srow][2 * t], hp1 = S[srow][2 * t + 1];
      float h0 = (1.f - z0) * n0 + z0 * hp0;
      float h1 = (1.f - z1) * n1 + z1 * hp1;
      mx0 = fmaxf(mx0, h0);
      mx1 = fmaxf(mx1, h1);
      if (istd) {
        S[idx][2 * t] = h0;
        S[idx][2 * t + 1] = h1;
        S2[idx][t] = packh2(h0, h1);
      } else if (par >= 0) {
        float c0 = S[par][2 * t] + h0;
        float c1 = S[par][2 * t + 1] + h1;
        S[par][2 * t] = c0;
        S[par][2 * t + 1] = c1;
        S2[par][t] = packh2(c0, c1);
      }
    }
    __syncthreads();
  }

  if (t < 128) {
    float2 o;
    o.x = mx0;
    o.y = mx1;
    *(float2*)(ctx + (size_t)b * 512 + istd * 256 + 2 * t) = o;
  }
}

// ---------------- fc1 + fc2 ----------------
__global__ __launch_bounds__(128) void final_k(const float* __restrict__ ctx_g,
                                               const float* __restrict__ fcW,
                                               const float* __restrict__ fcb,
                                               const float* __restrict__ fc2W,
                                               const float* __restrict__ fc2b,
                                               float* __restrict__ out) {
  const int b = blockIdx.x;
  const int t = threadIdx.x;
  __shared__ float ctx[512];
  __shared__ float f1[100];
  for (int i = t; i < 512; i += 128) ctx[i] = ctx_g[(size_t)b * 512 + i];
  __syncthreads();
  if (t < 100) {
    float a = fcb[t];
    for (int k = 0; k < 512; ++k) a = fmaf(ctx[k], fcW[k * 100 + t], a);
    f1[t] = a;
  }
  __syncthreads();
  if (t < 5) {
    float a = fc2b[t];
    for (int k = 0; k < 100; ++k) a = fmaf(f1[k], fc2W[k * 5 + t], a);
    out[b * 5 + t] = a;
  }
}

extern "C" void kernel_launch(void* const* d_in, const int* in_sizes, int n_in, void* d_out,
                              int out_size, void* d_ws, size_t ws_size, hipStream_t stream) {
  const int* xs = (const int*)d_in[0];
  const int* heads = (const int*)d_in[1];
  const int* rels = (const int*)d_in[2];
  const int* labels = (const int*)d_in[3];
  const float* emb_W = (const float*)d_in[9];
  const float* rel_W = (const float*)d_in[10];
  const float* Wi_f = (const float*)d_in[11];
  const float* Wh_f = (const float*)d_in[12];
  const float* bi_f = (const float*)d_in[13];
  const float* bh_f = (const float*)d_in[14];
  const float* Wi_b = (const float*)d_in[15];
  const float* Wh_b = (const float*)d_in[16];
  const float* bi_b = (const float*)d_in[17];
  const float* bh_b = (const float*)d_in[18];
  const float* Wt = (const float*)d_in[19];
  const float* bt = (const float*)d_in[20];
  const float* dt_Wx = (const float*)d_in[21];
  const float* dt_Uh = (const float*)d_in[22];
  const float* dt_b = (const float*)d_in[23];
  const float* td_Wx = (const float*)d_in[24];
  const float* td_Uh = (const float*)d_in[25];
  const float* td_b = (const float*)d_in[26];
  const float* fc_W = (const float*)d_in[27];
  const float* fc_b = (const float*)d_in[28];
  const float* fc2_W = (const float*)d_in[29];
  const float* fc2_b = (const float*)d_in[30];

  float* ws = (float*)d_ws;
  float* emb = ws;                  // 2048*512
  float* xp_f = ws + 1048576;       // 2048*768
  float* xp_b = xp_f + 1572864;     // 2048*768
  float* grus = xp_b + 1572864;     // 2048*512
  float* outputs = grus + 1048576;  // 2048*512
  float* ctx = outputs + 1048576;   // 32*512
  float* xp_dt = xp_f;              // alias (xp_f dead after gru_scan)
  float* xp_td = xp_b;              // alias

  gather_emb<<<2048, 128, 0, stream>>>(xs, labels, emb_W, emb);
  matmul_f32<<<dim3(12, 32), 256, 0, stream>>>(emb, Wi_f, bi_f, xp_f, 512, 768, 512, 768);
  matmul_f32<<<dim3(12, 32), 256, 0, stream>>>(emb, Wi_b, bi_b, xp_b, 512, 768, 512, 768);
  gru_scan<<<64, 512, 0, stream>>>(Wh_f, Wh_b, bh_f, bh_b, xp_f, xp_b, grus);
  gather_rel<<<2048, 64, 0, stream>>>(rels, rel_W, outputs);
  matmul_f32<<<dim3(4, 32), 256, 0, stream>>>(grus, Wt, bt, outputs, 512, 256, 512, 512);
  matmul_f32<<<dim3(12, 32), 256, 0, stream>>>(outputs, dt_Wx, dt_b, xp_dt, 512, 768, 512, 768);
  matmul_f32<<<dim3(12, 32), 256, 0, stream>>>(outputs, td_Wx, td_b, xp_td, 512, 768, 512, 768);
  tree_scan<<<64, 512, 0, stream>>>(dt_Uh, td_Uh, xp_dt, xp_td, heads, ctx);
  final_k<<<32, 128, 0, stream>>>(ctx, fc_W, fc_b, fc2_W, fc2_b, (float*)d_out);
}

// Round 5
// 412.800 us; speedup vs baseline: 1.1747x; 1.1736x over previous
//
#include <hip/hip_runtime.h>

// Encoder: emb-gather -> xp matmuls -> BiGRU scan -> Wt matmul ->
// dt/td tree-GRU scans (fused maxpool) -> fc1 + fc2.
// Scans: 1 block of 1024 threads per (batch, dir/kind). Recurrent weights f16
// packed in THREE ext_vector<32 x u32> = 96 VGPRs/thread (fits under the
// 128-VGPR cap the backend enforces regardless of launch bounds; rounds 1-4
// needed 192 -> forced spill -> L2-scratch-bound at ~170us/scan).
// Thread (q2, j): owns output col j for all 3 gates, k-quarter q2.
// Dots via v_dot2_f32_f16; f32 carry path (identical numerics to r1-r4).

typedef _Float16 half2v __attribute__((ext_vector_type(2)));
typedef unsigned int u32x32 __attribute__((ext_vector_type(32)));

__device__ __forceinline__ float fdot2f(unsigned int a, unsigned int b, float c) {
#if __has_builtin(__builtin_amdgcn_fdot2)
  return __builtin_amdgcn_fdot2(__builtin_bit_cast(half2v, a),
                                __builtin_bit_cast(half2v, b), c, false);
#else
  half2v av = __builtin_bit_cast(half2v, a), bv = __builtin_bit_cast(half2v, b);
  return c + (float)av.x * (float)bv.x + (float)av.y * (float)bv.y;
#endif
}

__device__ __forceinline__ unsigned int packh2(float x, float y) {
  half2v p;
  p.x = (_Float16)x;
  p.y = (_Float16)y;
  return __builtin_bit_cast(unsigned int, p);
}

__device__ __forceinline__ float sigm(float x) { return 1.f / (1.f + __expf(-x)); }
__device__ __forceinline__ float tanh_fast(float x) {
  float cx = fminf(fmaxf(x, -15.f), 15.f);
  float e = __expf(2.f * cx);
  return (e - 1.f) / (e + 1.f);
}

// Thread's weight block: gate g col (g*256+j), k rows [k0, k0+64) as 32 pairs.
#define LOAD_WVEC3(Wsrc)                                                       \
  {                                                                            \
    const float* Wb = (Wsrc) + (size_t)k0 * 768 + j;                           \
    _Pragma("unroll") for (int kk = 0; kk < 32; ++kk) {                        \
      const float* r0p = Wb + (size_t)(2 * kk) * 768;                          \
      const float* r1p = Wb + (size_t)(2 * kk + 1) * 768;                      \
      w0[kk] = packh2(r0p[0], r1p[0]);                                         \
      w1[kk] = packh2(r0p[256], r1p[256]);                                     \
      w2[kk] = packh2(r0p[512], r1p[512]);                                     \
    }                                                                          \
  }

// Dot phase: read 32 packed h pairs from LDS (8 x b128), 96 dot2, write parts.
// HSRC: _Float16* at this thread's k0 (16B-aligned).
#define DOT_PHASE3(HSRC)                                                       \
  {                                                                            \
    float a0 = 0.f, a1 = 0.f, a2 = 0.f;                                        \
    const uint4* hv = (const uint4*)(HSRC);                                    \
    _Pragma("unroll") for (int bq = 0; bq < 8; ++bq) {                         \
      uint4 u = hv[bq];                                                        \
      a0 = fdot2f(w0[4 * bq + 0], u.x, a0);                                    \
      a1 = fdot2f(w1[4 * bq + 0], u.x, a1);                                    \
      a2 = fdot2f(w2[4 * bq + 0], u.x, a2);                                    \
      a0 = fdot2f(w0[4 * bq + 1], u.y, a0);                                    \
      a1 = fdot2f(w1[4 * bq + 1], u.y, a1);                                    \
      a2 = fdot2f(w2[4 * bq + 1], u.y, a2);                                    \
      a0 = fdot2f(w0[4 * bq + 2], u.z, a0);                                    \
      a1 = fdot2f(w1[4 * bq + 2], u.z, a1);                                    \
      a2 = fdot2f(w2[4 * bq + 2], u.z, a2);                                    \
      a0 = fdot2f(w0[4 * bq + 3], u.w, a0);                                    \
      a1 = fdot2f(w1[4 * bq + 3], u.w, a1);                                    \
      a2 = fdot2f(w2[4 * bq + 3], u.w, a2);                                    \
    }                                                                          \
    part[q2][0][j] = a0;                                                       \
    part[q2][1][j] = a1;                                                       \
    part[q2][2][j] = a2;                                                       \
  }

// ---------------- embedding gathers ----------------
__global__ void gather_emb(const int* __restrict__ xs, const int* __restrict__ labels,
                           const float* __restrict__ embW, float* __restrict__ emb) {
  const int row = blockIdx.x;
  const int t = threadIdx.x;
  const float4* W4 = (const float4*)embW;
  float4* dst = (float4*)(emb + (size_t)row * 512);
  if (t < 64)
    dst[t] = W4[(size_t)xs[row] * 64 + t];
  else
    dst[t] = W4[(size_t)labels[row] * 64 + (t - 64)];
}

__global__ void gather_rel(const int* __restrict__ rels, const float* __restrict__ relW,
                           float* __restrict__ outputs) {
  const int row = blockIdx.x;
  const int t = threadIdx.x;  // 64
  const float4* W4 = (const float4*)relW;
  float4* dst = (float4*)(outputs + (size_t)row * 512 + 256);
  dst[t] = W4[(size_t)rels[row] * 64 + t];
}

// ---------------- generic f32 tiled matmul: C[M,N] = A[M,K]@W[K,N] + bias ----------------
__global__ __launch_bounds__(256, 2) void matmul_f32(const float* __restrict__ A,
                                                     const float* __restrict__ W,
                                                     const float* __restrict__ bias,
                                                     float* __restrict__ C, int K, int N,
                                                     int lda, int ldc) {
  __shared__ float As[16][68];
  __shared__ float Bs[16][64];
  const int t = threadIdx.x;
  const int bm = blockIdx.y * 64, bn = blockIdx.x * 64;
  const int tn4 = (t & 15) * 4, tm4 = (t >> 4) * 4;
  const int lm = t >> 2, lk4 = (t & 3) * 4;
  const int wk = t >> 4, wn4 = (t & 15) * 4;
  float acc[4][4] = {};
  for (int kt = 0; kt < K; kt += 16) {
    float4 a4 = *(const float4*)(A + (size_t)(bm + lm) * lda + kt + lk4);
    As[lk4 + 0][lm] = a4.x;
    As[lk4 + 1][lm] = a4.y;
    As[lk4 + 2][lm] = a4.z;
    As[lk4 + 3][lm] = a4.w;
    *(float4*)(&Bs[wk][wn4]) = *(const float4*)(W + (size_t)(kt + wk) * N + bn + wn4);
    __syncthreads();
#pragma unroll
    for (int k = 0; k < 16; ++k) {
      float4 av = *(const float4*)(&As[k][tm4]);
      float4 bv = *(const float4*)(&Bs[k][tn4]);
      float aa[4] = {av.x, av.y, av.z, av.w};
      float bb[4] = {bv.x, bv.y, bv.z, bv.w};
#pragma unroll
      for (int i = 0; i < 4; ++i)
#pragma unroll
        for (int j = 0; j < 4; ++j) acc[i][j] = fmaf(aa[i], bb[j], acc[i][j]);
    }
    __syncthreads();
  }
#pragma unroll
  for (int i = 0; i < 4; ++i) {
    float4 o;
    o.x = acc[i][0] + bias[bn + tn4 + 0];
    o.y = acc[i][1] + bias[bn + tn4 + 1];
    o.z = acc[i][2] + bias[bn + tn4 + 2];
    o.w = acc[i][3] + bias[bn + tn4 + 3];
    *(float4*)(C + (size_t)(bm + tm4 + i) * ldc + bn + tn4) = o;
  }
}

// ---------------- BiGRU scan: 1 block (1024 thr) per (batch, dir) ----------------
__global__ __launch_bounds__(1024, 4) void gru_scan(
    const float* __restrict__ Wh_f, const float* __restrict__ Wh_b,
    const float* __restrict__ bh_f, const float* __restrict__ bh_b,
    const float* __restrict__ xp_f, const float* __restrict__ xp_b,
    float* __restrict__ grus_cat) {
  const int b = blockIdx.x & 31;
  const int dir = blockIdx.x >> 5;
  const float* __restrict__ Wh = dir ? Wh_b : Wh_f;
  const float* __restrict__ bh = dir ? bh_b : bh_f;
  const float* __restrict__ xp = dir ? xp_b : xp_f;

  __shared__ __align__(16) _Float16 h1[256];  // f16 h state (scalar layout)
  __shared__ float part[4][3][256];           // [kquarter][gate][j]

  const int t = threadIdx.x;
  const int j = t & 255;
  const int q2 = t >> 8;
  const int k0 = q2 * 64;

  u32x32 w0, w1, w2;
  LOAD_WVEC3(Wh);

  float br = 0.f, bz = 0.f, bn = 0.f, hprev = 0.f;
  if (t < 256) {
    br = bh[j];
    bz = bh[256 + j];
    bn = bh[512 + j];
    h1[j] = (_Float16)0.f;
  }
  __syncthreads();

  for (int s = 0; s < 64; ++s) {
    const int nn = dir ? (63 - s) : s;
    float xr, xz, xn_;
    if (t < 256) {
      const float* xrow = xp + (size_t)(b * 64 + nn) * 768;
      xr = xrow[j];
      xz = xrow[256 + j];
      xn_ = xrow[512 + j];
    }

    DOT_PHASE3(h1 + k0);
    __syncthreads();

    if (t < 256) {
      float sr = 0.f, sz = 0.f, sn = 0.f;
#pragma unroll
      for (int q = 0; q < 4; ++q) {
        sr += part[q][0][j];
        sz += part[q][1][j];
        sn += part[q][2][j];
      }
      float r = sigm(xr + sr + br);
      float z = sigm(xz + sz + bz);
      float n = tanh_fast(xn_ + r * (sn + bn));
      float h = (1.f - z) * n + z * hprev;
      hprev = h;
      h1[j] = (_Float16)h;
      grus_cat[(size_t)(b * 64 + nn) * 512 + dir * 256 + j] = h;
    }
    __syncthreads();
  }
}

// ---------------- tree scans with fused maxpool: 1 block (1024 thr) per (batch, kind) ----------------
__global__ __launch_bounds__(1024, 4) void tree_scan(
    const float* __restrict__ Uh_dt, const float* __restrict__ Uh_td,
    const float* __restrict__ xp_dt, const float* __restrict__ xp_td,
    const int* __restrict__ heads, float* __restrict__ ctx) {
  const int b = blockIdx.x & 31;
  const int istd = blockIdx.x >> 5;  // 0 = dt (bottom-up), 1 = td (top-down)
  const float* __restrict__ Uh = istd ? Uh_td : Uh_dt;
  const float* __restrict__ xp = istd ? xp_td : xp_dt;

  __shared__ float S[65][256];                     // f32 state (C or Hout); row 64 = zeros
  __shared__ __align__(16) _Float16 S2[65][256];   // f16 mirror (scalar layout)
  __shared__ float part[4][3][256];
  __shared__ int hd[64];

  const int t = threadIdx.x;
  const int j = t & 255;
  const int q2 = t >> 8;
  const int k0 = q2 * 64;

  u32x32 w0, w1, w2;
  LOAD_WVEC3(Uh);

  for (int i = t; i < 65 * 256; i += 1024) ((float*)S)[i] = 0.f;
  for (int i = t; i < 65 * 256; i += 1024) ((_Float16*)S2)[i] = (_Float16)0.f;
  if (t < 64) hd[t] = heads[b * 64 + t];
  __syncthreads();

  float mx = -1e30f;  // running maxpool (t < 256)

  for (int s = 0; s < 64; ++s) {
    const int idx = istd ? s : (63 - s);
    const int par = hd[idx];
    const int srow = istd ? (par >= 0 ? par : 64) : idx;

    float xr, xz, xn_;
    if (t < 256) {
      const float* xrow = xp + (size_t)(b * 64 + idx) * 768;
      xr = xrow[j];
      xz = xrow[256 + j];
      xn_ = xrow[512 + j];
    }

    DOT_PHASE3(&S2[srow][k0]);
    __syncthreads();

    if (t < 256) {
      float sr = 0.f, sz = 0.f, sn = 0.f;
#pragma unroll
      for (int q = 0; q < 4; ++q) {
        sr += part[q][0][j];
        sz += part[q][1][j];
        sn += part[q][2][j];
      }
      float r = sigm(xr + sr);
      float z = sigm(xz + sz);
      float n = tanh_fast(xn_ + r * sn);
      float hp = S[srow][j];
      float h = (1.f - z) * n + z * hp;
      mx = fmaxf(mx, h);
      if (istd) {
        S[idx][j] = h;
        S2[idx][j] = (_Float16)h;
      } else if (par >= 0) {
        float c = S[par][j] + h;
        S[par][j] = c;
        S2[par][j] = (_Float16)c;
      }
    }
    __syncthreads();
  }

  if (t < 256) ctx[(size_t)b * 512 + istd * 256 + j] = mx;
}

// ---------------- fc1 + fc2 ----------------
__global__ __launch_bounds__(128) void final_k(const float* __restrict__ ctx_g,
                                               const float* __restrict__ fcW,
                                               const float* __restrict__ fcb,
                                               const float* __restrict__ fc2W,
                                               const float* __restrict__ fc2b,
                                               float* __restrict__ out) {
  const int b = blockIdx.x;
  const int t = threadIdx.x;
  __shared__ float ctx[512];
  __shared__ float f1[100];
  for (int i = t; i < 512; i += 128) ctx[i] = ctx_g[(size_t)b * 512 + i];
  __syncthreads();
  if (t < 100) {
    float a = fcb[t];
    for (int k = 0; k < 512; ++k) a = fmaf(ctx[k], fcW[k * 100 + t], a);
    f1[t] = a;
  }
  __syncthreads();
  if (t < 5) {
    float a = fc2b[t];
    for (int k = 0; k < 100; ++k) a = fmaf(f1[k], fc2W[k * 5 + t], a);
    out[b * 5 + t] = a;
  }
}

extern "C" void kernel_launch(void* const* d_in, const int* in_sizes, int n_in, void* d_out,
                              int out_size, void* d_ws, size_t ws_size, hipStream_t stream) {
  const int* xs = (const int*)d_in[0];
  const int* heads = (const int*)d_in[1];
  const int* rels = (const int*)d_in[2];
  const int* labels = (const int*)d_in[3];
  const float* emb_W = (const float*)d_in[9];
  const float* rel_W = (const float*)d_in[10];
  const float* Wi_f = (const float*)d_in[11];
  const float* Wh_f = (const float*)d_in[12];
  const float* bi_f = (const float*)d_in[13];
  const float* bh_f = (const float*)d_in[14];
  const float* Wi_b = (const float*)d_in[15];
  const float* Wh_b = (const float*)d_in[16];
  const float* bi_b = (const float*)d_in[17];
  const float* bh_b = (const float*)d_in[18];
  const float* Wt = (const float*)d_in[19];
  const float* bt = (const float*)d_in[20];
  const float* dt_Wx = (const float*)d_in[21];
  const float* dt_Uh = (const float*)d_in[22];
  const float* dt_b = (const float*)d_in[23];
  const float* td_Wx = (const float*)d_in[24];
  const float* td_Uh = (const float*)d_in[25];
  const float* td_b = (const float*)d_in[26];
  const float* fc_W = (const float*)d_in[27];
  const float* fc_b = (const float*)d_in[28];
  const float* fc2_W = (const float*)d_in[29];
  const float* fc2_b = (const float*)d_in[30];

  float* ws = (float*)d_ws;
  float* emb = ws;                  // 2048*512
  float* xp_f = ws + 1048576;       // 2048*768
  float* xp_b = xp_f + 1572864;     // 2048*768
  float* grus = xp_b + 1572864;     // 2048*512
  float* outputs = grus + 1048576;  // 2048*512
  float* ctx = outputs + 1048576;   // 32*512
  float* xp_dt = xp_f;              // alias (xp_f dead after gru_scan)
  float* xp_td = xp_b;              // alias

  gather_emb<<<2048, 128, 0, stream>>>(xs, labels, emb_W, emb);
  matmul_f32<<<dim3(12, 32), 256, 0, stream>>>(emb, Wi_f, bi_f, xp_f, 512, 768, 512, 768);
  matmul_f32<<<dim3(12, 32), 256, 0, stream>>>(emb, Wi_b, bi_b, xp_b, 512, 768, 512, 768);
  gru_scan<<<64, 1024, 0, stream>>>(Wh_f, Wh_b, bh_f, bh_b, xp_f, xp_b, grus);
  gather_rel<<<2048, 64, 0, stream>>>(rels, rel_W, outputs);
  matmul_f32<<<dim3(4, 32), 256, 0, stream>>>(grus, Wt, bt, outputs, 512, 256, 512, 512);
  matmul_f32<<<dim3(12, 32), 256, 0, stream>>>(outputs, dt_Wx, dt_b, xp_dt, 512, 768, 512, 768);
  matmul_f32<<<dim3(12, 32), 256, 0, stream>>>(outputs, td_Wx, td_b, xp_td, 512, 768, 512, 768);
  tree_scan<<<64, 1024, 0, stream>>>(dt_Uh, td_Uh, xp_dt, xp_td, heads, ctx);
  final_k<<<32, 128, 0, stream>>>(ctx, fc_W, fc_b, fc2_W, fc2_b, (float*)d_out);
}